// Round 3
// baseline (408.208 us; speedup 1.0000x reference)
//
#include <hip/hip_runtime.h>
#include <hip/hip_bf16.h>
#include <math.h>

#define ALPHA 0.01f

typedef __bf16 bf16x8 __attribute__((ext_vector_type(8)));
typedef float  floatx4 __attribute__((ext_vector_type(4)));

static __device__ __forceinline__ unsigned short f2bf_bits(float f) {
    return __builtin_bit_cast(unsigned short, (__bf16)f);   // RNE
}

// 16-lane (DPP row) reductions — pure VALU, no LDS traffic.
template <int CTRL>
static __device__ __forceinline__ float dppmov(float x) {
    int r = __builtin_amdgcn_update_dpp(0, __builtin_bit_cast(int, x), CTRL, 0xf, 0xf, false);
    return __builtin_bit_cast(float, r);
}
static __device__ __forceinline__ float red16min(float x) {
    x = fminf(x, dppmov<0x121>(x)); x = fminf(x, dppmov<0x122>(x));
    x = fminf(x, dppmov<0x124>(x)); x = fminf(x, dppmov<0x128>(x));
    return x;
}
static __device__ __forceinline__ float red16max(float x) {
    x = fmaxf(x, dppmov<0x121>(x)); x = fmaxf(x, dppmov<0x122>(x));
    x = fmaxf(x, dppmov<0x124>(x)); x = fmaxf(x, dppmov<0x128>(x));
    return x;
}
static __device__ __forceinline__ float red16sum(float x) {
    x += dppmov<0x121>(x); x += dppmov<0x122>(x);
    x += dppmov<0x124>(x); x += dppmov<0x128>(x);
    return x;
}

static __device__ __forceinline__ uint4 pack8(float4 f0, float4 f1) {
    uint4 pk;
    pk.x = (unsigned)f2bf_bits(f0.x) | ((unsigned)f2bf_bits(f0.y) << 16);
    pk.y = (unsigned)f2bf_bits(f0.z) | ((unsigned)f2bf_bits(f0.w) << 16);
    pk.z = (unsigned)f2bf_bits(f1.x) | ((unsigned)f2bf_bits(f1.y) << 16);
    pk.w = (unsigned)f2bf_bits(f1.z) | ((unsigned)f2bf_bits(f1.w) << 16);
    return pk;
}

// ---------------------------------------------------------------------------
// Histogram entropy of a wave's 16-row tile held in acc[CTN] (post-activation).
// Quad q owns rows q*4+reg. cc = this quad's private count row.
// Returns wave-summed H (valid in all lanes).
// ---------------------------------------------------------------------------
template <int DOUT>
static __device__ __forceinline__ float entropy_tile(const floatx4* acc,
        unsigned int* cc, int lane16)
{
    constexpr int CTN   = DOUT / 16;
    constexpr int HALF  = DOUT / 2;
    constexpr int LOG2D = (DOUT == 256) ? 8 : (DOUT == 128) ? 7 : 5;
    constexpr float LOGB = (DOUT == 256) ? 5.54517744f
                         : (DOUT == 128) ? 4.85203026f : 3.46573590f;
    float Hq = 0.0f;
    #pragma unroll
    for (int reg = 0; reg < 4; reg++) {
        float mn = acc[0][reg], mx = mn;
        #pragma unroll
        for (int ct = 1; ct < CTN; ct++) {
            mn = fminf(mn, acc[ct][reg]);
            mx = fmaxf(mx, acc[ct][reg]);
        }
        mn = red16min(mn);
        mx = red16max(mx);
        float wdt = mx - mn;
        float scale = (float)DOUT / (wdt > 0.0f ? wdt : 1.0f);

        #pragma unroll
        for (int i = 0; i < DOUT / 32; i++) cc[lane16 + 16 * i] = 0u;
        // in-wave DS program order: zeros -> atomics -> reads

        #pragma unroll
        for (int ct = 0; ct < CTN; ct++) {
            int b = (int)((acc[ct][reg] - mn) * scale);
            b = b < (DOUT - 1) ? b : (DOUT - 1);
            atomicAdd(&cc[b & (HALF - 1)],
                      1u << (((b >> (LOG2D - 1)) & 1) << 4));
        }

        float s = 0.0f;
        #pragma unroll
        for (int i = 0; i < DOUT / 32; i++) {
            unsigned int word = cc[lane16 + 16 * i];
            int c0 = (int)(word & 0xffffu), c1 = (int)(word >> 16);
            if (c0 > 0) { float p = (float)c0 * (1.0f / (float)DOUT); s += p * __logf(p); }
            if (c1 > 0) { float p = (float)c1 * (1.0f / (float)DOUT); s += p * __logf(p); }
        }
        s = red16sum(s);
        Hq += LOGB - s;
    }
    Hq += __shfl_xor(Hq, 16, 64);
    Hq += __shfl_xor(Hq, 32, 64);
    return Hq;
}

// ---------------------------------------------------------------------------
// One tail layer: acc = A @ W^T (bias via C-init, leaky), write swizzled yt
// for the next layer, return entropy partial. A-frags supplied in regs.
// B-frags straight from global Wf slots (L1/L2-cached, coalesced).
// ---------------------------------------------------------------------------
template <int DIN, int DOUT>
static __device__ __forceinline__ float tail_layer(const bf16x8* a,
    char* __restrict__ yt,
    const unsigned short* __restrict__ Wf, const float* __restrict__ bias,
    unsigned int* __restrict__ cc, int lane)
{
    constexpr int KT = DIN / 32, CTN = DOUT / 16, NCO = DOUT / 8;
    const int lane16 = lane & 15, q = lane >> 4;

    floatx4 acc[CTN];
    #pragma unroll
    for (int ct = 0; ct < CTN; ct++) acc[ct] = (floatx4)(bias[ct * 16 + lane16]);

    #pragma unroll
    for (int kt = 0; kt < KT; kt++) {
        #pragma unroll
        for (int ct = 0; ct < CTN; ct++) {
            bf16x8 bw = *(const bf16x8*)(Wf + ((size_t)(kt * CTN + ct) * 64 + lane) * 8);
            acc[ct] = __builtin_amdgcn_mfma_f32_16x16x32_bf16(a[kt], bw, acc[ct], 0, 0, 0);
        }
    }

    #pragma unroll
    for (int ct = 0; ct < CTN; ct++) {
        #pragma unroll
        for (int reg = 0; reg < 4; reg++) {
            float v = acc[ct][reg];
            v = v > 0.0f ? v : ALPHA * v;
            acc[ct][reg] = v;
            int r  = q * 4 + reg;
            int c  = (ct * 16 + lane16) >> 3;
            int cs = c ^ (r & (NCO - 1));
            *(unsigned short*)(yt + r * (DOUT * 2) + cs * 16 + (lane16 & 7) * 2)
                = f2bf_bits(v);
        }
    }
    return entropy_tile<DOUT>(acc, cc, lane16);
}

// Load A-frags for a DIN-wide layer from the wave's swizzled yt tile.
template <int DIN>
static __device__ __forceinline__ void load_afrags(bf16x8* a,
    const char* __restrict__ yt, int lane16, int q)
{
    constexpr int KT = DIN / 32, NCI = DIN / 8;
    // previous layer's ds_writes precede these reads (in-wave DS order);
    // the asm fence also stops the compiler reordering across the alias.
    asm volatile("s_waitcnt lgkmcnt(0)" ::: "memory");
    #pragma unroll
    for (int kt = 0; kt < KT; kt++) {
        int cs = (kt * 4 + q) ^ (lane16 & (NCI - 1));
        a[kt] = *(const bf16x8*)(yt + lane16 * (DIN * 2) + cs * 16);
    }
    asm volatile("s_waitcnt lgkmcnt(0)" ::: "memory");
}

// ---------------------------------------------------------------------------
// Megakernel, ZERO barriers: every wave independently runs its 16 rows
// through L1..L6. L1 A-frags are per-lane global loads of X (wave-coalesced
// 16 rows x 128 B); ALL W fragments come straight from global (L2-resident).
// yts is per-wave-private LDS; entropy counts are per-(wave,quad)-private.
// ---------------------------------------------------------------------------
__global__ __launch_bounds__(256, 4) void mega(
    const float* __restrict__ X,
    const unsigned short* __restrict__ W1f, const float* __restrict__ b1,
    const unsigned short* __restrict__ W2f, const float* __restrict__ b2,
    const unsigned short* __restrict__ W3f, const float* __restrict__ b3,
    const unsigned short* __restrict__ W4f, const float* __restrict__ b4,
    const unsigned short* __restrict__ W5f, const float* __restrict__ b5,
    const float* __restrict__ W6, const float* __restrict__ b6,
    float* __restrict__ out, float* __restrict__ Hpart)
{
    __shared__ __align__(16) char yts[4][4096];   // per-wave Y tile
    __shared__ unsigned int cnt[16][129];         // per-(wave,quad) counts

    const int t = threadIdx.x;
    const int lane = t & 63, lane16 = lane & 15, q = lane >> 4, w = t >> 6;
    const int row0 = blockIdx.x * 64;
    const int myrow = w * 16 + lane16;
    unsigned int* cc = cnt[w * 4 + q];
    char* yt = yts[w];
    const int hidx = blockIdx.x * 4 + w;

    // ================= L1: 784 -> 256, barrier-free ========================
    floatx4 acc1[16];
    #pragma unroll
    for (int ct = 0; ct < 16; ct++) acc1[ct] = (floatx4)(b1[ct * 16 + lane16]);
    {
        const float* Xr = X + (size_t)(row0 + myrow) * 784;
        float4 fa0 = *(const float4*)(Xr + q * 8);
        float4 fa1 = *(const float4*)(Xr + q * 8 + 4);
        #pragma unroll 1
        for (int kt = 0; kt < 24; kt++) {
            bf16x8 a = __builtin_bit_cast(bf16x8, pack8(fa0, fa1));
            // prefetch next ktile's A (kt==23 -> clamp cols for the 16-wide tail)
            int noff = (kt == 23) ? ((q & 1) * 8) : (q * 8);
            const float* nsrc = Xr + (kt + 1) * 32 + noff;
            fa0 = *(const float4*)(nsrc);
            fa1 = *(const float4*)(nsrc + 4);
            #pragma unroll
            for (int ct = 0; ct < 16; ct++) {
                bf16x8 bw = *(const bf16x8*)(W1f + ((size_t)(kt * 16 + ct) * 64 + lane) * 8);
                acc1[ct] = __builtin_amdgcn_mfma_f32_16x16x32_bf16(a, bw, acc1[ct], 0, 0, 0);
            }
        }
        // tail ktile kt=24: cols 768..783 valid for q<2; zero for q>=2
        uint4 pk = pack8(fa0, fa1);
        if (q >= 2) { pk.x = 0u; pk.y = 0u; pk.z = 0u; pk.w = 0u; }
        bf16x8 a = __builtin_bit_cast(bf16x8, pk);
        #pragma unroll
        for (int ct = 0; ct < 16; ct++) {
            bf16x8 bw = *(const bf16x8*)(W1f + ((size_t)(24 * 16 + ct) * 64 + lane) * 8);
            acc1[ct] = __builtin_amdgcn_mfma_f32_16x16x32_bf16(a, bw, acc1[ct], 0, 0, 0);
        }
    }

    // leaky_relu in registers
    #pragma unroll
    for (int ct = 0; ct < 16; ct++) {
        #pragma unroll
        for (int reg = 0; reg < 4; reg++) {
            float v = acc1[ct][reg];
            acc1[ct][reg] = v > 0.0f ? v : ALPHA * v;
        }
    }

    float H = entropy_tile<256>(acc1, cc, lane16);
    if (lane == 0) Hpart[0 * 4096 + hidx] = H;

    // ===== intra-wave transpose: L1 C-layout -> L2 A-frags, 2 half-passes ===
    bf16x8 a2[8];
    #pragma unroll
    for (int p = 0; p < 2; p++) {
        #pragma unroll
        for (int ct = 0; ct < 8; ct++) {
            #pragma unroll
            for (int reg = 0; reg < 4; reg++) {
                int r  = q * 4 + reg;
                int c  = (ct * 16 + lane16) >> 3;     // chunk within half
                int cs = c ^ r;                       // 16 chunks -> r&15 == r
                *(unsigned short*)(yt + r * 256 + cs * 16 + (lane16 & 7) * 2)
                    = f2bf_bits(acc1[p * 8 + ct][reg]);
            }
        }
        asm volatile("s_waitcnt lgkmcnt(0)" ::: "memory");
        #pragma unroll
        for (int kt = 0; kt < 4; kt++) {
            int cs = (kt * 4 + q) ^ lane16;
            a2[p * 4 + kt] = *(const bf16x8*)(yt + lane16 * 256 + cs * 16);
        }
        asm volatile("s_waitcnt lgkmcnt(0)" ::: "memory");
    }

    // ================= L2..L5: barrier-free chain ==========================
    H = tail_layer<256, 128>(a2, yt, W2f, b2, cc, lane);
    if (lane == 0) Hpart[1 * 4096 + hidx] = H;

    bf16x8 a[4];
    load_afrags<128>(a, yt, lane16, q);
    H = tail_layer<128, 128>(a, yt, W3f, b3, cc, lane);
    if (lane == 0) Hpart[2 * 4096 + hidx] = H;

    load_afrags<128>(a, yt, lane16, q);
    H = tail_layer<128, 128>(a, yt, W4f, b4, cc, lane);
    if (lane == 0) Hpart[3 * 4096 + hidx] = H;

    load_afrags<128>(a, yt, lane16, q);
    H = tail_layer<128, 32>(a, yt, W5f, b5, cc, lane);
    if (lane == 0) Hpart[4 * 4096 + hidx] = H;

    // ================= L6: log_softmax(relu(x @ W6^T + b6)) ================
    // row = lane16 of this wave's tile; outputs j split across quads (3,3,3,1)
    asm volatile("s_waitcnt lgkmcnt(0)" ::: "memory");
    float x6[32];
    #pragma unroll
    for (int c = 0; c < 4; c++) {
        int cs = c ^ (lane16 & 3);
        bf16x8 v = *(const bf16x8*)(yt + lane16 * 64 + cs * 16);
        #pragma unroll
        for (int j = 0; j < 8; j++) x6[c * 8 + j] = (float)v[j];
    }

    float z[3];
    float m = -1e30f;
    #pragma unroll
    for (int s2 = 0; s2 < 3; s2++) {
        int jj = q * 3 + s2;
        float a6 = 0.0f;
        if (jj < 10) {
            a6 = b6[jj];
            #pragma unroll
            for (int k = 0; k < 32; k++) a6 = fmaf(x6[k], W6[jj * 32 + k], a6);
            a6 = fmaxf(a6, 0.0f);
            m = fmaxf(m, a6);
        }
        z[s2] = a6;
    }
    m = fmaxf(m, __shfl_xor(m, 16, 64));
    m = fmaxf(m, __shfl_xor(m, 32, 64));
    float se = 0.0f;
    #pragma unroll
    for (int s2 = 0; s2 < 3; s2++)
        if (q * 3 + s2 < 10) se += __expf(z[s2] - m);
    se += __shfl_xor(se, 16, 64);
    se += __shfl_xor(se, 32, 64);
    float ls = __logf(se);
    const size_t ro = (size_t)(row0 + w * 16 + lane16) * 10;
    #pragma unroll
    for (int s2 = 0; s2 < 3; s2++) {
        int jj = q * 3 + s2;
        if (jj < 10) out[ro + jj] = z[s2] - m - ls;
    }
}

// ---------------------------------------------------------------------------
// fp32 W1..W5 -> bf16 fragment-major slots, concatenated into ws. (unchanged)
// ---------------------------------------------------------------------------
__global__ void convert_wfrag(const float* __restrict__ W1, const float* __restrict__ W2,
                              const float* __restrict__ W3, const float* __restrict__ W4,
                              const float* __restrict__ W5, unsigned short* __restrict__ out)
{
    int s = blockIdx.x * 256 + threadIdx.x;
    if (s >= 34304) return;
    const float* W; int DIN, CTN, sl;
    if      (s < 25600) { W = W1; DIN = 784; CTN = 16; sl = s;         }
    else if (s < 29696) { W = W2; DIN = 256; CTN = 8;  sl = s - 25600; }
    else if (s < 31744) { W = W3; DIN = 128; CTN = 8;  sl = s - 29696; }
    else if (s < 33792) { W = W4; DIN = 128; CTN = 8;  sl = s - 31744; }
    else                { W = W5; DIN = 128; CTN = 2;  sl = s - 33792; }
    int kt = sl / (CTN * 64);
    int ct = (sl / 64) % CTN;
    int ln = sl & 63;
    int r  = ct * 16 + (ln & 15);
    int k0 = kt * 32 + (ln >> 4) * 8;
    unsigned short v[8];
    #pragma unroll
    for (int j = 0; j < 8; j++) {
        int k = k0 + j;
        v[j] = (k < DIN) ? f2bf_bits(W[(size_t)r * DIN + k]) : (unsigned short)0;
    }
    uint4 pk;
    pk.x = (unsigned)v[0] | ((unsigned)v[1] << 16);
    pk.y = (unsigned)v[2] | ((unsigned)v[3] << 16);
    pk.z = (unsigned)v[4] | ((unsigned)v[5] << 16);
    pk.w = (unsigned)v[6] | ((unsigned)v[7] << 16);
    *(uint4*)(out + (size_t)s * 8) = pk;
}

// ---------------------------------------------------------------------------
// Final entropy reduction: block l sums layer l's 4096 wave partials.
// ---------------------------------------------------------------------------
__global__ __launch_bounds__(256) void hreduce(const float* __restrict__ Hp,
                                               float* __restrict__ out_tail)
{
    __shared__ float sm[4];
    const int t = threadIdx.x, lane = t & 63, w = t >> 6;
    const int l = blockIdx.x;
    const float* p = Hp + (size_t)l * 4096;
    float s = 0.0f;
    for (int i = t; i < 4096; i += 256) s += p[i];
    #pragma unroll
    for (int off = 1; off <= 32; off <<= 1) s += __shfl_xor(s, off, 64);
    if (lane == 0) sm[w] = s;
    __syncthreads();
    if (t == 0)
        out_tail[l] = (sm[0] + sm[1] + sm[2] + sm[3]) * (1.0f / 65536.0f);
}

// ---------------------------------------------------------------------------
extern "C" void kernel_launch(void* const* d_in, const int* in_sizes, int n_in,
                              void* d_out, int out_size, void* d_ws, size_t ws_size,
                              hipStream_t stream)
{
    const float* x  = (const float*)d_in[0];
    const float* W1 = (const float*)d_in[1];  const float* b1 = (const float*)d_in[2];
    const float* W2 = (const float*)d_in[3];  const float* b2 = (const float*)d_in[4];
    const float* W3 = (const float*)d_in[5];  const float* b3 = (const float*)d_in[6];
    const float* W4 = (const float*)d_in[7];  const float* b4 = (const float*)d_in[8];
    const float* W5 = (const float*)d_in[9];  const float* b5 = (const float*)d_in[10];
    const float* W6 = (const float*)d_in[11]; const float* b6 = (const float*)d_in[12];
    float* out = (float*)d_out;

    constexpr int B = 65536;
    char* ws = (char*)d_ws;
    float* Hpart = (float*)ws;                             // 5*4096 floats = 80 KB
    unsigned short* Wfrag = (unsigned short*)(ws + 81920); // 34304 slots * 16 B
    unsigned short* W1f = Wfrag;                           // 25600 slots
    unsigned short* W2f = W1f + 25600 * 8;
    unsigned short* W3f = W2f + 4096 * 8;
    unsigned short* W4f = W3f + 2048 * 8;
    unsigned short* W5f = W4f + 2048 * 8;

    convert_wfrag<<<134, 256, 0, stream>>>(W1, W2, W3, W4, W5, Wfrag);

    mega<<<B / 64, 256, 0, stream>>>(
        x, W1f, b1, W2f, b2, W3f, b3, W4f, b4, W5f, b5, W6, b6, out, Hpart);

    hreduce<<<5, 256, 0, stream>>>(Hpart, out + (size_t)B * 10);
}

// Round 4
// 390.099 us; speedup vs baseline: 1.0464x; 1.0464x over previous
//
#include <hip/hip_runtime.h>
#include <hip/hip_bf16.h>
#include <math.h>

#define ALPHA 0.01f

typedef __bf16 bf16x8 __attribute__((ext_vector_type(8)));
typedef float  floatx4 __attribute__((ext_vector_type(4)));

static __device__ __forceinline__ unsigned short f2bf_bits(float f) {
    return __builtin_bit_cast(unsigned short, (__bf16)f);   // RNE
}

// async global->LDS, 16 B per lane, zero destination VGPRs.
// NOTE: lds pointer must be wave-uniform; data lands at base + lane*16.
static __device__ __forceinline__ void glds16(const void* g, void* l) {
    __builtin_amdgcn_global_load_lds(
        (const __attribute__((address_space(1))) unsigned int*)g,
        (__attribute__((address_space(3))) unsigned int*)l, 16, 0, 0);
}

// 16-lane (DPP row) reductions — pure VALU, no LDS traffic.
template <int CTRL>
static __device__ __forceinline__ float dppmov(float x) {
    int r = __builtin_amdgcn_update_dpp(0, __builtin_bit_cast(int, x), CTRL, 0xf, 0xf, false);
    return __builtin_bit_cast(float, r);
}
static __device__ __forceinline__ float red16min(float x) {
    x = fminf(x, dppmov<0x121>(x)); x = fminf(x, dppmov<0x122>(x));
    x = fminf(x, dppmov<0x124>(x)); x = fminf(x, dppmov<0x128>(x));
    return x;
}
static __device__ __forceinline__ float red16max(float x) {
    x = fmaxf(x, dppmov<0x121>(x)); x = fmaxf(x, dppmov<0x122>(x));
    x = fmaxf(x, dppmov<0x124>(x)); x = fmaxf(x, dppmov<0x128>(x));
    return x;
}
static __device__ __forceinline__ float red16sum(float x) {
    x += dppmov<0x121>(x); x += dppmov<0x122>(x);
    x += dppmov<0x124>(x); x += dppmov<0x128>(x);
    return x;
}

static __device__ __forceinline__ uint4 pack8(float4 f0, float4 f1) {
    uint4 pk;
    pk.x = (unsigned)f2bf_bits(f0.x) | ((unsigned)f2bf_bits(f0.y) << 16);
    pk.y = (unsigned)f2bf_bits(f0.z) | ((unsigned)f2bf_bits(f0.w) << 16);
    pk.z = (unsigned)f2bf_bits(f1.x) | ((unsigned)f2bf_bits(f1.y) << 16);
    pk.w = (unsigned)f2bf_bits(f1.z) | ((unsigned)f2bf_bits(f1.w) << 16);
    return pk;
}

// ---------------------------------------------------------------------------
// Histogram entropy of a wave's 16-row tile held in acc[CTN] (post-activation).
// Quad q owns rows q*4+reg. cc = this quad's private count row.
// Returns wave-summed H (valid in all lanes).
// ---------------------------------------------------------------------------
template <int DOUT>
static __device__ __forceinline__ float entropy_tile(const floatx4* acc,
        unsigned int* cc, int lane16)
{
    constexpr int CTN   = DOUT / 16;
    constexpr int HALF  = DOUT / 2;
    constexpr int LOG2D = (DOUT == 256) ? 8 : (DOUT == 128) ? 7 : 5;
    constexpr float LOGB = (DOUT == 256) ? 5.54517744f
                         : (DOUT == 128) ? 4.85203026f : 3.46573590f;
    float Hq = 0.0f;
    #pragma unroll
    for (int reg = 0; reg < 4; reg++) {
        float mn = acc[0][reg], mx = mn;
        #pragma unroll
        for (int ct = 1; ct < CTN; ct++) {
            mn = fminf(mn, acc[ct][reg]);
            mx = fmaxf(mx, acc[ct][reg]);
        }
        mn = red16min(mn);
        mx = red16max(mx);
        float wdt = mx - mn;
        float scale = (float)DOUT / (wdt > 0.0f ? wdt : 1.0f);

        #pragma unroll
        for (int i = 0; i < DOUT / 32; i++) cc[lane16 + 16 * i] = 0u;
        // in-wave DS program order: zeros -> atomics -> reads

        #pragma unroll
        for (int ct = 0; ct < CTN; ct++) {
            int b = (int)((acc[ct][reg] - mn) * scale);
            b = b < (DOUT - 1) ? b : (DOUT - 1);
            atomicAdd(&cc[b & (HALF - 1)],
                      1u << (((b >> (LOG2D - 1)) & 1) << 4));
        }

        float s = 0.0f;
        #pragma unroll
        for (int i = 0; i < DOUT / 32; i++) {
            unsigned int word = cc[lane16 + 16 * i];
            int c0 = (int)(word & 0xffffu), c1 = (int)(word >> 16);
            if (c0 > 0) { float p = (float)c0 * (1.0f / (float)DOUT); s += p * __logf(p); }
            if (c1 > 0) { float p = (float)c1 * (1.0f / (float)DOUT); s += p * __logf(p); }
        }
        s = red16sum(s);
        Hq += LOGB - s;
    }
    Hq += __shfl_xor(Hq, 16, 64);
    Hq += __shfl_xor(Hq, 32, 64);
    return Hq;
}

// ---------------------------------------------------------------------------
// One tail layer: acc = A @ W^T (bias via C-init, leaky), write swizzled yt
// for the next layer, return entropy partial. A-frags supplied in regs.
// B-frags straight from global Wf slots (L1/L2-cached, coalesced).
// ---------------------------------------------------------------------------
template <int DIN, int DOUT>
static __device__ __forceinline__ float tail_layer(const bf16x8* a,
    char* __restrict__ yt,
    const unsigned short* __restrict__ Wf, const float* __restrict__ bias,
    unsigned int* __restrict__ cc, int lane)
{
    constexpr int KT = DIN / 32, CTN = DOUT / 16, NCO = DOUT / 8;
    const int lane16 = lane & 15, q = lane >> 4;

    floatx4 acc[CTN];
    #pragma unroll
    for (int ct = 0; ct < CTN; ct++) acc[ct] = (floatx4)(bias[ct * 16 + lane16]);

    #pragma unroll
    for (int kt = 0; kt < KT; kt++) {
        #pragma unroll
        for (int ct = 0; ct < CTN; ct++) {
            bf16x8 bw = *(const bf16x8*)(Wf + ((size_t)(kt * CTN + ct) * 64 + lane) * 8);
            acc[ct] = __builtin_amdgcn_mfma_f32_16x16x32_bf16(a[kt], bw, acc[ct], 0, 0, 0);
        }
    }

    #pragma unroll
    for (int ct = 0; ct < CTN; ct++) {
        #pragma unroll
        for (int reg = 0; reg < 4; reg++) {
            float v = acc[ct][reg];
            v = v > 0.0f ? v : ALPHA * v;
            acc[ct][reg] = v;
            int r  = q * 4 + reg;
            int c  = (ct * 16 + lane16) >> 3;
            int cs = c ^ (r & (NCO - 1));
            *(unsigned short*)(yt + r * (DOUT * 2) + cs * 16 + (lane16 & 7) * 2)
                = f2bf_bits(v);
        }
    }
    return entropy_tile<DOUT>(acc, cc, lane16);
}

// Load A-frags for a DIN-wide layer from the wave's swizzled yt tile.
template <int DIN>
static __device__ __forceinline__ void load_afrags(bf16x8* a,
    const char* __restrict__ yt, int lane16, int q)
{
    constexpr int KT = DIN / 32, NCI = DIN / 8;
    // previous layer's ds_writes precede these reads (in-wave DS order);
    // the asm fence also stops the compiler reordering across the alias.
    asm volatile("s_waitcnt lgkmcnt(0)" ::: "memory");
    #pragma unroll
    for (int kt = 0; kt < KT; kt++) {
        int cs = (kt * 4 + q) ^ (lane16 & (NCI - 1));
        a[kt] = *(const bf16x8*)(yt + lane16 * (DIN * 2) + cs * 16);
    }
    asm volatile("s_waitcnt lgkmcnt(0)" ::: "memory");
}

// ---------------------------------------------------------------------------
// Megakernel. L1: block-shared W1 double-buffered in LDS (2-phase pipeline:
// STAGE(kt+1) issued BEFORE compute(kt); one waitcnt+barrier per ktile, so
// the stage latency hides under the compute phase — not the R2 drain loop).
// After L1's last barrier the 32KB W region is reused as {yts | cnt} and the
// tail L2..L6 runs completely barrier-free per wave (R3 structure).
// ---------------------------------------------------------------------------
__global__ __launch_bounds__(256, 4) void mega(
    const float* __restrict__ X,
    const unsigned short* __restrict__ W1f, const float* __restrict__ b1,
    const unsigned short* __restrict__ W2f, const float* __restrict__ b2,
    const unsigned short* __restrict__ W3f, const float* __restrict__ b3,
    const unsigned short* __restrict__ W4f, const float* __restrict__ b4,
    const unsigned short* __restrict__ W5f, const float* __restrict__ b5,
    const float* __restrict__ W6, const float* __restrict__ b6,
    float* __restrict__ out, float* __restrict__ Hpart)
{
    // [0,16K)+[16K,32K): W1 double buffer during L1;
    // afterwards: [0,16K) = yts[4][4096], [16K,16K+8256) = cnt[16][129].
    __shared__ __align__(16) char region[32768];

    const int t = threadIdx.x;
    const int lane = t & 63, lane16 = lane & 15, q = lane >> 4, w = t >> 6;
    const int row0 = blockIdx.x * 64;
    const int myrow = w * 16 + lane16;
    const int hidx = blockIdx.x * 4 + w;

    // ================= L1: 784 -> 256, 2-phase pipelined W staging =========
    floatx4 acc1[16];
    #pragma unroll
    for (int ct = 0; ct < 16; ct++) acc1[ct] = (floatx4)(b1[ct * 16 + lane16]);

    {
        // stage one 16KB W ktile: 1024 slots; wave w stages slots
        // [w*256, w*256+256) with a wave-uniform LDS base (glds requirement).
        auto stageW = [&](int kt2, char* buf) {
            #pragma unroll
            for (int i = 0; i < 4; i++)
                glds16(W1f + ((size_t)kt2 * 1024 + w * 256 + i * 64 + lane) * 8,
                       buf + (w * 256 + i * 64) * 16);
        };

        const float* Xr = X + (size_t)(row0 + myrow) * 784;

        stageW(0, region);                       // prologue: ktile0 -> buf0
        float4 fa0 = *(const float4*)(Xr + q * 8);
        float4 fa1 = *(const float4*)(Xr + q * 8 + 4);
        asm volatile("s_waitcnt vmcnt(0) lgkmcnt(0)" ::: "memory");
        __builtin_amdgcn_s_barrier();

        #pragma unroll 1
        for (int kt = 0; kt < 24; kt++) {
            char* bufC = region + ((kt & 1) << 14);
            char* bufN = region + ((~kt & 1) << 14);
            stageW(kt + 1, bufN);                // issue BEFORE compute (overlap)

            bf16x8 a = __builtin_bit_cast(bf16x8, pack8(fa0, fa1));
            // prefetch next ktile's A (kt==23 -> clamp cols for 16-wide tail)
            int noff = (kt == 23) ? ((q & 1) * 8) : (q * 8);
            const float* nsrc = Xr + (kt + 1) * 32 + noff;
            fa0 = *(const float4*)(nsrc);
            fa1 = *(const float4*)(nsrc + 4);

            #pragma unroll
            for (int ct = 0; ct < 16; ct++) {
                bf16x8 bw = *(const bf16x8*)(bufC + (ct * 64 + lane) * 16);
                acc1[ct] = __builtin_amdgcn_mfma_f32_16x16x32_bf16(a, bw, acc1[ct], 0, 0, 0);
            }
            // drain this phase's stage (issued a full compute ago) + ds reads,
            // then align: next phase may overwrite bufC.
            asm volatile("s_waitcnt vmcnt(0) lgkmcnt(0)" ::: "memory");
            __builtin_amdgcn_s_barrier();
        }

        // tail ktile kt=24 (staged into buf0 during kt=23): cols 768..783
        // valid for q<2; zero for q>=2.
        uint4 pk = pack8(fa0, fa1);
        if (q >= 2) { pk.x = 0u; pk.y = 0u; pk.z = 0u; pk.w = 0u; }
        bf16x8 a = __builtin_bit_cast(bf16x8, pk);
        #pragma unroll
        for (int ct = 0; ct < 16; ct++) {
            bf16x8 bw = *(const bf16x8*)(region + (ct * 64 + lane) * 16);
            acc1[ct] = __builtin_amdgcn_mfma_f32_16x16x32_bf16(a, bw, acc1[ct], 0, 0, 0);
        }
        asm volatile("s_waitcnt lgkmcnt(0)" ::: "memory");
        __builtin_amdgcn_s_barrier();            // W region dead -> reuse below
    }

    char* yt = region + w * 4096;
    unsigned int* cc = (unsigned int*)(region + 16384) + (w * 4 + q) * 129;

    // leaky_relu in registers
    #pragma unroll
    for (int ct = 0; ct < 16; ct++) {
        #pragma unroll
        for (int reg = 0; reg < 4; reg++) {
            float v = acc1[ct][reg];
            acc1[ct][reg] = v > 0.0f ? v : ALPHA * v;
        }
    }

    float H = entropy_tile<256>(acc1, cc, lane16);
    if (lane == 0) Hpart[0 * 4096 + hidx] = H;

    // ===== intra-wave transpose: L1 C-layout -> L2 A-frags, 2 half-passes ===
    bf16x8 a2[8];
    #pragma unroll
    for (int p = 0; p < 2; p++) {
        #pragma unroll
        for (int ct = 0; ct < 8; ct++) {
            #pragma unroll
            for (int reg = 0; reg < 4; reg++) {
                int r  = q * 4 + reg;
                int c  = (ct * 16 + lane16) >> 3;     // chunk within half
                int cs = c ^ r;                       // 16 chunks -> r&15 == r
                *(unsigned short*)(yt + r * 256 + cs * 16 + (lane16 & 7) * 2)
                    = f2bf_bits(acc1[p * 8 + ct][reg]);
            }
        }
        asm volatile("s_waitcnt lgkmcnt(0)" ::: "memory");
        #pragma unroll
        for (int kt = 0; kt < 4; kt++) {
            int cs = (kt * 4 + q) ^ lane16;
            a2[p * 4 + kt] = *(const bf16x8*)(yt + lane16 * 256 + cs * 16);
        }
        asm volatile("s_waitcnt lgkmcnt(0)" ::: "memory");
    }

    // ================= L2..L5: barrier-free chain ==========================
    H = tail_layer<256, 128>(a2, yt, W2f, b2, cc, lane);
    if (lane == 0) Hpart[1 * 4096 + hidx] = H;

    bf16x8 a[4];
    load_afrags<128>(a, yt, lane16, q);
    H = tail_layer<128, 128>(a, yt, W3f, b3, cc, lane);
    if (lane == 0) Hpart[2 * 4096 + hidx] = H;

    load_afrags<128>(a, yt, lane16, q);
    H = tail_layer<128, 128>(a, yt, W4f, b4, cc, lane);
    if (lane == 0) Hpart[3 * 4096 + hidx] = H;

    load_afrags<128>(a, yt, lane16, q);
    H = tail_layer<128, 32>(a, yt, W5f, b5, cc, lane);
    if (lane == 0) Hpart[4 * 4096 + hidx] = H;

    // ================= L6: log_softmax(relu(x @ W6^T + b6)) ================
    // row = lane16 of this wave's tile; outputs j split across quads (3,3,3,1)
    asm volatile("s_waitcnt lgkmcnt(0)" ::: "memory");
    float x6[32];
    #pragma unroll
    for (int c = 0; c < 4; c++) {
        int cs = c ^ (lane16 & 3);
        bf16x8 v = *(const bf16x8*)(yt + lane16 * 64 + cs * 16);
        #pragma unroll
        for (int j = 0; j < 8; j++) x6[c * 8 + j] = (float)v[j];
    }

    float z[3];
    float m = -1e30f;
    #pragma unroll
    for (int s2 = 0; s2 < 3; s2++) {
        int jj = q * 3 + s2;
        float a6 = 0.0f;
        if (jj < 10) {
            a6 = b6[jj];
            #pragma unroll
            for (int k = 0; k < 32; k++) a6 = fmaf(x6[k], W6[jj * 32 + k], a6);
            a6 = fmaxf(a6, 0.0f);
            m = fmaxf(m, a6);
        }
        z[s2] = a6;
    }
    m = fmaxf(m, __shfl_xor(m, 16, 64));
    m = fmaxf(m, __shfl_xor(m, 32, 64));
    float se = 0.0f;
    #pragma unroll
    for (int s2 = 0; s2 < 3; s2++)
        if (q * 3 + s2 < 10) se += __expf(z[s2] - m);
    se += __shfl_xor(se, 16, 64);
    se += __shfl_xor(se, 32, 64);
    float ls = __logf(se);
    const size_t ro = (size_t)(row0 + w * 16 + lane16) * 10;
    #pragma unroll
    for (int s2 = 0; s2 < 3; s2++) {
        int jj = q * 3 + s2;
        if (jj < 10) out[ro + jj] = z[s2] - m - ls;
    }
}

// ---------------------------------------------------------------------------
// fp32 W1..W5 -> bf16 fragment-major slots, concatenated into ws. (unchanged)
// ---------------------------------------------------------------------------
__global__ void convert_wfrag(const float* __restrict__ W1, const float* __restrict__ W2,
                              const float* __restrict__ W3, const float* __restrict__ W4,
                              const float* __restrict__ W5, unsigned short* __restrict__ out)
{
    int s = blockIdx.x * 256 + threadIdx.x;
    if (s >= 34304) return;
    const float* W; int DIN, CTN, sl;
    if      (s < 25600) { W = W1; DIN = 784; CTN = 16; sl = s;         }
    else if (s < 29696) { W = W2; DIN = 256; CTN = 8;  sl = s - 25600; }
    else if (s < 31744) { W = W3; DIN = 128; CTN = 8;  sl = s - 29696; }
    else if (s < 33792) { W = W4; DIN = 128; CTN = 8;  sl = s - 31744; }
    else                { W = W5; DIN = 128; CTN = 2;  sl = s - 33792; }
    int kt = sl / (CTN * 64);
    int ct = (sl / 64) % CTN;
    int ln = sl & 63;
    int r  = ct * 16 + (ln & 15);
    int k0 = kt * 32 + (ln >> 4) * 8;
    unsigned short v[8];
    #pragma unroll
    for (int j = 0; j < 8; j++) {
        int k = k0 + j;
        v[j] = (k < DIN) ? f2bf_bits(W[(size_t)r * DIN + k]) : (unsigned short)0;
    }
    uint4 pk;
    pk.x = (unsigned)v[0] | ((unsigned)v[1] << 16);
    pk.y = (unsigned)v[2] | ((unsigned)v[3] << 16);
    pk.z = (unsigned)v[4] | ((unsigned)v[5] << 16);
    pk.w = (unsigned)v[6] | ((unsigned)v[7] << 16);
    *(uint4*)(out + (size_t)s * 8) = pk;
}

// ---------------------------------------------------------------------------
// Final entropy reduction: block l sums layer l's 4096 wave partials.
// ---------------------------------------------------------------------------
__global__ __launch_bounds__(256) void hreduce(const float* __restrict__ Hp,
                                               float* __restrict__ out_tail)
{
    __shared__ float sm[4];
    const int t = threadIdx.x, lane = t & 63, w = t >> 6;
    const int l = blockIdx.x;
    const float* p = Hp + (size_t)l * 4096;
    float s = 0.0f;
    for (int i = t; i < 4096; i += 256) s += p[i];
    #pragma unroll
    for (int off = 1; off <= 32; off <<= 1) s += __shfl_xor(s, off, 64);
    if (lane == 0) sm[w] = s;
    __syncthreads();
    if (t == 0)
        out_tail[l] = (sm[0] + sm[1] + sm[2] + sm[3]) * (1.0f / 65536.0f);
}

// ---------------------------------------------------------------------------
extern "C" void kernel_launch(void* const* d_in, const int* in_sizes, int n_in,
                              void* d_out, int out_size, void* d_ws, size_t ws_size,
                              hipStream_t stream)
{
    const float* x  = (const float*)d_in[0];
    const float* W1 = (const float*)d_in[1];  const float* b1 = (const float*)d_in[2];
    const float* W2 = (const float*)d_in[3];  const float* b2 = (const float*)d_in[4];
    const float* W3 = (const float*)d_in[5];  const float* b3 = (const float*)d_in[6];
    const float* W4 = (const float*)d_in[7];  const float* b4 = (const float*)d_in[8];
    const float* W5 = (const float*)d_in[9];  const float* b5 = (const float*)d_in[10];
    const float* W6 = (const float*)d_in[11]; const float* b6 = (const float*)d_in[12];
    float* out = (float*)d_out;

    constexpr int B = 65536;
    char* ws = (char*)d_ws;
    float* Hpart = (float*)ws;                             // 5*4096 floats = 80 KB
    unsigned short* Wfrag = (unsigned short*)(ws + 81920); // 34304 slots * 16 B
    unsigned short* W1f = Wfrag;                           // 25600 slots
    unsigned short* W2f = W1f + 25600 * 8;
    unsigned short* W3f = W2f + 4096 * 8;
    unsigned short* W4f = W3f + 2048 * 8;
    unsigned short* W5f = W4f + 2048 * 8;

    convert_wfrag<<<134, 256, 0, stream>>>(W1, W2, W3, W4, W5, Wfrag);

    mega<<<B / 64, 256, 0, stream>>>(
        x, W1f, b1, W2f, b2, W3f, b3, W4f, b4, W5f, b5, W6, b6, out, Hpart);

    hreduce<<<5, 256, 0, stream>>>(Hpart, out + (size_t)B * 10);
}